// Round 11
// baseline (66.456 us; speedup 1.0000x reference)
//
#include <hip/hip_runtime.h>
#include <hip/hip_bf16.h>

typedef __attribute__((ext_vector_type(8))) short short8;
typedef __attribute__((ext_vector_type(4))) float f32x4;

#define NB 8
#define LQ 2048
#define LK 2048
#define DIN 1024
#define MROWS (NB * LQ)   // 16384

static constexpr float KSCALE = 0.022097086912079608f; // 1/sqrt(2048)

__device__ __forceinline__ ushort f2bf(float f) {
    union { float f; unsigned int u; } v; v.f = f;
    unsigned int r = v.u + 0x7FFFu + ((v.u >> 16) & 1u);   // RNE
    return (ushort)(r >> 16);
}
__device__ __forceinline__ float bf2f(ushort u) {
    union { unsigned int u; float f; } v; v.u = ((unsigned int)u) << 16;
    return v.f;
}
__device__ __forceinline__ unsigned pk2(float lo, float hi) {
    __hip_bfloat162 h = __float22bfloat162_rn(float2{lo, hi});   // v_cvt_pk_bf16_f32
    union { __hip_bfloat162 h; unsigned u; } c; c.h = h; return c.u;
}
__device__ __forceinline__ short8 cvt8(float4 lo, float4 hi) {
    union { short8 s; unsigned u[4]; } r;
    r.u[0] = pk2(lo.x, lo.y);
    r.u[1] = pk2(lo.z, lo.w);
    r.u[2] = pk2(hi.x, hi.y);
    r.u[3] = pk2(hi.z, hi.w);
    return r.s;
}

// async global->LDS, 16B per lane; LDS dst is wave-uniform base + lane*16
__device__ __forceinline__ void gl16(const void* g, void* l) {
    __builtin_amdgcn_global_load_lds(
        (const __attribute__((address_space(1))) void*)g,
        (__attribute__((address_space(3))) void*)l, 16, 0, 0);
}

// ---------------------------------------------------------------------------
// prep: Wt[p][n][k] = bf16(W_p[k][n])  (transpose+convert, LDS tiled)
// ---------------------------------------------------------------------------
__global__ __launch_bounds__(256) void prep_kernel(
    const float* __restrict__ Wq, const float* __restrict__ Wk,
    const float* __restrict__ Wv, ushort* __restrict__ Wt)
{
    const float* W = (blockIdx.z == 0) ? Wq : (blockIdx.z == 1) ? Wk : Wv;
    ushort* O = Wt + (size_t)blockIdx.z * 128 * 1024;
    const int k0 = blockIdx.x * 64, n0 = blockIdx.y * 64;
    __shared__ float tile[64][65];
    const int t = threadIdx.x;
    {
        const int r = t >> 4, c = (t & 15) * 4;
        #pragma unroll
        for (int i = 0; i < 4; ++i) {
            float4 v = *(const float4*)&W[(size_t)(k0 + r + i * 16) * 128 + n0 + c];
            tile[r + i * 16][c + 0] = v.x; tile[r + i * 16][c + 1] = v.y;
            tile[r + i * 16][c + 2] = v.z; tile[r + i * 16][c + 3] = v.w;
        }
    }
    __syncthreads();
    {
        const int n = t >> 2, kc = (t & 3) * 16;
        ushort tmp[16];
        #pragma unroll
        for (int j = 0; j < 16; ++j) tmp[j] = f2bf(tile[kc + j][n]);
        *(uint4*)&O[(size_t)(n0 + n) * 1024 + k0 + kc]     = *(uint4*)&tmp[0];
        *(uint4*)&O[(size_t)(n0 + n) * 1024 + k0 + kc + 8] = *(uint4*)&tmp[8];
    }
}

// ---------------------------------------------------------------------------
// proj: Y = bf16(relu(X[16384,1024] @ W + b))
// R10's 8-wave ring with DEPTH 4 and 2-stage-ahead prefetch: stage t+3 is
// issued at step t; FENCE(4) leaves TWO stages (4 loads/wave) in flight, so
// the awaited stage has ~2.2 step-times of latency cover (R10 had ~1.2 —
// replay showed proj is latency-exposure-bound, not BW/TLP-bound).
// LDS 64 KB (4 slots x [A 64x32 fp32 + B 128x32 bf16]) -> 2 blocks/CU,
// 16 waves/CU. All swizzle/fragment formulas identical to R6/R10.
// ---------------------------------------------------------------------------
__global__ __launch_bounds__(512, 4) void proj_kernel(
    const float* __restrict__ Xq, const float* __restrict__ bq,
    const float* __restrict__ Xk, const float* __restrict__ bk,
    const float* __restrict__ Xv, const float* __restrict__ bv,
    const ushort* __restrict__ Wt,
    ushort* __restrict__ qp, ushort* __restrict__ kp, ushort* __restrict__ vp)
{
    const int p = blockIdx.y;
    const float* X; const float* bias; ushort* Y;
    if (p == 0)      { X = Xq; bias = bq; Y = qp; }
    else if (p == 1) { X = Xk; bias = bk; Y = kp; }
    else             { X = Xv; bias = bv; Y = vp; }
    const ushort* W = Wt + (size_t)p * 131072;

    __shared__ __align__(16) float  As[4 * 2048];    // 32 KB: 4 slots 64x32 fp32
    __shared__ __align__(16) ushort Bs[4 * 4096];    // 32 KB: 4 slots 128x32 bf16

    const int tid  = threadIdx.x;
    const int lane = tid & 63;
    const int w    = tid >> 6;          // 0..7
    const int wr   = (w >> 1) * 16;     // wave row base: 0,16,32,48
    const int wc   = (w & 1) * 64;      // wave col base: 0,64
    const int row0 = blockIdx.x * 64;

    // ---- staging sources (inverse-swizzled per lane; R6 formula family) ----
    const int rA = w * 8 + (lane >> 3);
    const int cA = (lane & 7) ^ (lane >> 3);
    const float* gA = X + (size_t)(row0 + rA) * DIN + cA * 4;
    const int sB = w * 8 + (lane >> 3);
    const int cB = (lane & 7) ^ (lane >> 3);
    const int nB = 2 * sB + (cB >> 2);
    const ushort* gB = W + (size_t)nB * DIN + (cB & 3) * 8;

    // ---- fragment read offsets (swizzled; R6 family) ----
    const int col = lane & 15;
    const int kg  = (lane >> 4) * 8;
    const int c0  = kg >> 2;
    const int bc  = kg >> 3;
    const int ra  = wr + col;
    const int axr = ra & 7;
    const int aLo = ra * 32 + ((c0 ^ axr) << 2);
    const int aHi = ra * 32 + (((c0 + 1) ^ axr) << 2);
    const int nb0 = wc + col;
    const int bO  = (nb0 >> 1) * 64 +
                    (((((nb0 & 1) << 2) | bc) ^ ((nb0 >> 1) & 7)) << 3);

    f32x4 acc[4];
    #pragma unroll
    for (int ni = 0; ni < 4; ++ni) acc[ni] = (f32x4){0.f, 0.f, 0.f, 0.f};

#define STAGE(s_, t_) do {                                                    \
    gl16(gA + (t_) * 32, &As[(s_) * 2048 + w * 256]);                         \
    gl16(gB + (t_) * 32, &Bs[(s_) * 4096 + w * 512]);                         \
} while (0)

#define STEP(s_) do {                                                         \
    float4 lo = *(const float4*)&As[(s_) * 2048 + aLo];                       \
    float4 hi = *(const float4*)&As[(s_) * 2048 + aHi];                       \
    short8 bf0 = *(const short8*)&Bs[(s_) * 4096 + bO];                       \
    short8 bf1 = *(const short8*)&Bs[(s_) * 4096 + bO + 512];                 \
    short8 bf2 = *(const short8*)&Bs[(s_) * 4096 + bO + 1024];                \
    short8 bf3 = *(const short8*)&Bs[(s_) * 4096 + bO + 1536];                \
    short8 af0 = cvt8(lo, hi);                                                \
    acc[0] = __builtin_amdgcn_mfma_f32_16x16x32_bf16(af0, bf0, acc[0], 0, 0, 0); \
    acc[1] = __builtin_amdgcn_mfma_f32_16x16x32_bf16(af0, bf1, acc[1], 0, 0, 0); \
    acc[2] = __builtin_amdgcn_mfma_f32_16x16x32_bf16(af0, bf2, acc[2], 0, 0, 0); \
    acc[3] = __builtin_amdgcn_mfma_f32_16x16x32_bf16(af0, bf3, acc[3], 0, 0, 0); \
} while (0)

#define FENCE(n_) do {                                                        \
    asm volatile("s_waitcnt vmcnt(" #n_ ")" ::: "memory");                    \
    __builtin_amdgcn_sched_barrier(0);                                        \
    __builtin_amdgcn_s_barrier();                                             \
    __builtin_amdgcn_sched_barrier(0);                                        \
} while (0)

    // prologue: 3 stages in flight; wait for stage 0 only
    STAGE(0, 0);
    STAGE(1, 1);
    STAGE(2, 2);
    FENCE(4);

    #pragma unroll 1
    for (int t = 0; t < 28; t += 4) {
        STAGE(3, t + 3); STEP(0); FENCE(4);
        STAGE(0, t + 4); STEP(1); FENCE(4);
        STAGE(1, t + 5); STEP(2); FENCE(4);
        STAGE(2, t + 6); STEP(3); FENCE(4);
    }
    // tail: steps 28..31
    STAGE(3, 31); STEP(0); FENCE(4);
    STEP(1); FENCE(2);
    STEP(2); FENCE(0);
    STEP(3);
    __syncthreads();    // all ring reads done; LDS free for Ys reuse

#undef STAGE
#undef STEP
#undef FENCE

    float bb[4];
    #pragma unroll
    for (int ni = 0; ni < 4; ++ni) bb[ni] = bias[wc + ni * 16 + col];

    ushort* Ys = (ushort*)As;           // 64x128 bf16 = 16 KB
    const int orow4 = (lane >> 4) * 4;
    #pragma unroll
    for (int ni = 0; ni < 4; ++ni)
        #pragma unroll
        for (int j = 0; j < 4; ++j) {
            float v = fmaxf(acc[ni][j] + bb[ni], 0.f);
            const int rl = wr + orow4 + j;
            const int cl = wc + ni * 16 + col;
            Ys[(rl * 128 + cl) ^ ((rl & 15) << 3)] = f2bf(v);
        }
    __syncthreads();

    {
        const int r = tid >> 3, c = (tid & 7) * 16;
        const int swz = (r & 15) << 3;
        ushort* Yg = Y + (size_t)(row0 + r) * 128 + c;
        *(uint4*)&Yg[0] = *(const uint4*)&Ys[(r * 128 + c)     ^ swz];
        *(uint4*)&Yg[8] = *(const uint4*)&Ys[(r * 128 + c + 8) ^ swz];
    }
}

// ---------------------------------------------------------------------------
// ktv: per (batch, 64-row chunk): partial Mt_part[v][e] = sum_r v[r][v]*k[r][e]
// ---------------------------------------------------------------------------
__global__ __launch_bounds__(256) void ktv_kernel(
    const ushort* __restrict__ kp, const ushort* __restrict__ vp,
    ushort* __restrict__ part)
{
    const int b = blockIdx.y, chunk = blockIdx.x;
    const ushort* K = kp + ((size_t)b * LK + chunk * 64) * 128;
    const ushort* V = vp + ((size_t)b * LK + chunk * 64) * 128;
    ushort* P = part + ((size_t)(b * 32 + chunk)) * 16384;

    __shared__ __align__(16) ushort ks[64 * 128];
    __shared__ __align__(16) ushort vs[64 * 128];
    const int t = threadIdx.x;
    {
        const int r = t >> 2, cc = (t & 3) * 32;
        #pragma unroll
        for (int j = 0; j < 4; ++j) {
            *(uint4*)&ks[r * 128 + cc + j * 8] = *(const uint4*)&K[r * 128 + cc + j * 8];
            *(uint4*)&vs[r * 128 + cc + j * 8] = *(const uint4*)&V[r * 128 + cc + j * 8];
        }
    }
    __syncthreads();

    const int e0 = (t & 15) * 8;
    const int v0 = (t >> 4) * 8;
    float acc[8][8];
    #pragma unroll
    for (int i = 0; i < 8; ++i)
        #pragma unroll
        for (int j = 0; j < 8; ++j) acc[i][j] = 0.f;

    for (int r = 0; r < 64; ++r) {
        uint4 kf = *(const uint4*)&ks[r * 128 + e0];
        uint4 vf = *(const uint4*)&vs[r * 128 + v0];
        const ushort* kw = (const ushort*)&kf;
        const ushort* vw = (const ushort*)&vf;
        float ke[8], ve[8];
        #pragma unroll
        for (int j = 0; j < 8; ++j) { ke[j] = bf2f(kw[j]); ve[j] = bf2f(vw[j]); }
        #pragma unroll
        for (int i = 0; i < 8; ++i)
            #pragma unroll
            for (int j = 0; j < 8; ++j)
                acc[i][j] = fmaf(ve[i], ke[j], acc[i][j]);
    }

    #pragma unroll
    for (int i = 0; i < 8; ++i) {
        ushort tmp[8];
        #pragma unroll
        for (int j = 0; j < 8; ++j) tmp[j] = f2bf(acc[i][j]);
        *(uint4*)&P[(v0 + i) * 128 + e0] = *(uint4*)&tmp[0];
    }
}

// ---------------------------------------------------------------------------
// reduce: Mt[b][v*128+e] = bf16(KSCALE * sum_{c<32} part[b][c][v*128+e])
// ---------------------------------------------------------------------------
__global__ __launch_bounds__(256) void reduce_kernel(
    const ushort* __restrict__ part, ushort* __restrict__ Mt)
{
    const int g = blockIdx.x * 256 + threadIdx.x;
    const int b = g >> 14, idx = g & 16383;
    const ushort* P = part + (size_t)b * 32 * 16384 + idx;
    float s = 0.f;
    #pragma unroll
    for (int c = 0; c < 32; ++c) s += bf2f(P[(size_t)c * 16384]);
    Mt[g] = f2bf(s * KSCALE);
}

// ---------------------------------------------------------------------------
// qm: out[row][v] = sum_e qp[row][e] * Mt[b][v][e]
// ---------------------------------------------------------------------------
__global__ __launch_bounds__(256) void qm_kernel(
    const ushort* __restrict__ qp, const ushort* __restrict__ Mt,
    float* __restrict__ out)
{
    const int row0 = blockIdx.x * 64;
    const int b = row0 >> 11;
    const ushort* Q = qp + (size_t)row0 * 128;
    const ushort* M = Mt + (size_t)b * 16384;

    __shared__ __align__(16) ushort As[64 * 128];
    __shared__ __align__(16) ushort Bs[128 * 128];

    const int t = threadIdx.x;
    {
        const int r = t >> 2, cc = (t & 3) * 32;
        const int swz = (r & 15) << 3;
        #pragma unroll
        for (int j = 0; j < 4; ++j)
            *(uint4*)&As[(r * 128 + cc + j * 8) ^ swz] = *(const uint4*)&Q[r * 128 + cc + j * 8];
    }
    {
        const int r = t >> 1, cc = (t & 1) * 64;
        const int swz = (r & 15) << 3;
        #pragma unroll
        for (int j = 0; j < 8; ++j)
            *(uint4*)&Bs[(r * 128 + cc + j * 8) ^ swz] = *(const uint4*)&M[r * 128 + cc + j * 8];
    }
    __syncthreads();

    const int lane = t & 63;
    const int wcol = (t >> 6) * 32;
    const int col  = lane & 15;
    const int kgrp = (lane >> 4) * 8;
    const int fswz = col << 3;

    f32x4 acc[4][2];
    #pragma unroll
    for (int mi = 0; mi < 4; ++mi)
        #pragma unroll
        for (int ni = 0; ni < 2; ++ni)
            acc[mi][ni] = (f32x4){0.f, 0.f, 0.f, 0.f};

    #pragma unroll
    for (int kk = 0; kk < 4; ++kk) {
        const int kb = kk * 32 + kgrp;
        short8 af[4], bfv[2];
        #pragma unroll
        for (int mi = 0; mi < 4; ++mi)
            af[mi] = *(const short8*)&As[((mi * 16 + col) * 128 + kb) ^ fswz];
        #pragma unroll
        for (int ni = 0; ni < 2; ++ni)
            bfv[ni] = *(const short8*)&Bs[((wcol + ni * 16 + col) * 128 + kb) ^ fswz];
        #pragma unroll
        for (int mi = 0; mi < 4; ++mi)
            #pragma unroll
            for (int ni = 0; ni < 2; ++ni)
                acc[mi][ni] = __builtin_amdgcn_mfma_f32_16x16x32_bf16(
                    af[mi], bfv[ni], acc[mi][ni], 0, 0, 0);
    }

    const int orow = (lane >> 4) * 4;
    #pragma unroll
    for (int mi = 0; mi < 4; ++mi)
        #pragma unroll
        for (int ni = 0; ni < 2; ++ni)
            #pragma unroll
            for (int j = 0; j < 4; ++j)
                out[(size_t)(row0 + mi * 16 + orow + j) * 128 + wcol + ni * 16 + col] =
                    acc[mi][ni][j];
}

// ---------------------------------------------------------------------------
extern "C" void kernel_launch(void* const* d_in, const int* in_sizes, int n_in,
                              void* d_out, int out_size, void* d_ws, size_t ws_size,
                              hipStream_t stream)
{
    const float* query = (const float*)d_in[0];
    const float* key   = (const float*)d_in[1];
    const float* value = (const float*)d_in[2];
    const float* Wq    = (const float*)d_in[3];
    const float* bq    = (const float*)d_in[4];
    const float* Wk    = (const float*)d_in[5];
    const float* bk    = (const float*)d_in[6];
    const float* Wv    = (const float*)d_in[7];
    const float* bv    = (const float*)d_in[8];
    float* out = (float*)d_out;

    ushort* qp   = (ushort*)d_ws;                    // 16384*128 bf16
    ushort* kp   = qp + (size_t)MROWS * 128;
    ushort* vp   = kp + (size_t)MROWS * 128;
    ushort* Wt   = vp + (size_t)MROWS * 128;         // 3*128*1024 bf16
    ushort* part = Wt + (size_t)3 * 128 * 1024;      // 8*32*16384 bf16
    ushort* Mt   = part + (size_t)8 * 32 * 16384;    // 8*16384 bf16

    prep_kernel<<<dim3(16, 2, 3), 256, 0, stream>>>(Wq, Wk, Wv, Wt);
    proj_kernel<<<dim3(256, 3), 512, 0, stream>>>(query, bq, key, bk, value, bv,
                                                  Wt, qp, kp, vp);
    ktv_kernel<<<dim3(32, NB), 256, 0, stream>>>(kp, vp, part);
    reduce_kernel<<<512, 256, 0, stream>>>(part, Mt);
    qm_kernel<<<MROWS / 64, 256, 0, stream>>>(qp, Mt, out);
}

// Round 12
// 57.945 us; speedup vs baseline: 1.1469x; 1.1469x over previous
//
#include <hip/hip_runtime.h>
#include <hip/hip_bf16.h>

typedef __attribute__((ext_vector_type(8))) short short8;
typedef __attribute__((ext_vector_type(4))) float f32x4;

#define NB 8
#define LQ 2048
#define LK 2048
#define DIN 1024
#define MROWS (NB * LQ)   // 16384

static constexpr float KSCALE = 0.022097086912079608f; // 1/sqrt(2048)

__device__ __forceinline__ ushort f2bf(float f) {
    union { float f; unsigned int u; } v; v.f = f;
    unsigned int r = v.u + 0x7FFFu + ((v.u >> 16) & 1u);   // RNE
    return (ushort)(r >> 16);
}
__device__ __forceinline__ float bf2f(ushort u) {
    union { unsigned int u; float f; } v; v.u = ((unsigned int)u) << 16;
    return v.f;
}
__device__ __forceinline__ unsigned pk2(float lo, float hi) {
    __hip_bfloat162 h = __float22bfloat162_rn(float2{lo, hi});   // v_cvt_pk_bf16_f32
    union { __hip_bfloat162 h; unsigned u; } c; c.h = h; return c.u;
}
__device__ __forceinline__ short8 cvt8(float4 lo, float4 hi) {
    union { short8 s; unsigned u[4]; } r;
    r.u[0] = pk2(lo.x, lo.y);
    r.u[1] = pk2(lo.z, lo.w);
    r.u[2] = pk2(hi.x, hi.y);
    r.u[3] = pk2(hi.z, hi.w);
    return r.s;
}

// async global->LDS, 16B per lane; LDS dst is wave-uniform base + lane*16
__device__ __forceinline__ void gl16(const void* g, void* l) {
    __builtin_amdgcn_global_load_lds(
        (const __attribute__((address_space(1))) void*)g,
        (__attribute__((address_space(3))) void*)l, 16, 0, 0);
}

// ---------------------------------------------------------------------------
// prep: Wt[p][n][k] = bf16(W_p[k][n])  (transpose+convert, LDS tiled)
// ---------------------------------------------------------------------------
__global__ __launch_bounds__(256) void prep_kernel(
    const float* __restrict__ Wq, const float* __restrict__ Wk,
    const float* __restrict__ Wv, ushort* __restrict__ Wt)
{
    const float* W = (blockIdx.z == 0) ? Wq : (blockIdx.z == 1) ? Wk : Wv;
    ushort* O = Wt + (size_t)blockIdx.z * 128 * 1024;
    const int k0 = blockIdx.x * 64, n0 = blockIdx.y * 64;
    __shared__ float tile[64][65];
    const int t = threadIdx.x;
    {
        const int r = t >> 4, c = (t & 15) * 4;
        #pragma unroll
        for (int i = 0; i < 4; ++i) {
            float4 v = *(const float4*)&W[(size_t)(k0 + r + i * 16) * 128 + n0 + c];
            tile[r + i * 16][c + 0] = v.x; tile[r + i * 16][c + 1] = v.y;
            tile[r + i * 16][c + 2] = v.z; tile[r + i * 16][c + 3] = v.w;
        }
    }
    __syncthreads();
    {
        const int n = t >> 2, kc = (t & 3) * 16;
        ushort tmp[16];
        #pragma unroll
        for (int j = 0; j < 16; ++j) tmp[j] = f2bf(tile[kc + j][n]);
        *(uint4*)&O[(size_t)(n0 + n) * 1024 + k0 + kc]     = *(uint4*)&tmp[0];
        *(uint4*)&O[(size_t)(n0 + n) * 1024 + k0 + kc + 8] = *(uint4*)&tmp[8];
    }
}

// ---------------------------------------------------------------------------
// proj: R10's 8-wave ring VERBATIM (3-deep, BK=32, FENCE(2), 48 KB,
// 3 blocks/CU, 24 waves/CU — the measured-best structure).
// Epilogue change only: p=0 writes qp row-major (qm consumes rows);
// p=1/2 write kpT/vpT TRANSPOSED [e][16384] (ktv-MFMA consumes K=row
// contiguous). Transpose is a read-back of the already-swizzled Ys tile.
// ---------------------------------------------------------------------------
__global__ __launch_bounds__(512, 6) void proj_kernel(
    const float* __restrict__ Xq, const float* __restrict__ bq,
    const float* __restrict__ Xk, const float* __restrict__ bk,
    const float* __restrict__ Xv, const float* __restrict__ bv,
    const ushort* __restrict__ Wt,
    ushort* __restrict__ qp, ushort* __restrict__ kpT, ushort* __restrict__ vpT)
{
    const int p = blockIdx.y;
    const float* X; const float* bias; ushort* Y;
    if (p == 0)      { X = Xq; bias = bq; Y = qp; }
    else if (p == 1) { X = Xk; bias = bk; Y = kpT; }
    else             { X = Xv; bias = bv; Y = vpT; }
    const ushort* W = Wt + (size_t)p * 131072;

    __shared__ __align__(16) float  As[3 * 2048];    // 24 KB: 3 slots 64x32 fp32
    __shared__ __align__(16) ushort Bs[3 * 4096];    // 24 KB: 3 slots 128x32 bf16

    const int tid  = threadIdx.x;
    const int lane = tid & 63;
    const int w    = tid >> 6;          // 0..7
    const int wr   = (w >> 1) * 16;     // wave row base: 0,16,32,48
    const int wc   = (w & 1) * 64;      // wave col base: 0,64
    const int row0 = blockIdx.x * 64;

    const int rA = w * 8 + (lane >> 3);
    const int cA = (lane & 7) ^ (lane >> 3);
    const float* gA = X + (size_t)(row0 + rA) * DIN + cA * 4;
    const int sB = w * 8 + (lane >> 3);
    const int cB = (lane & 7) ^ (lane >> 3);
    const int nB = 2 * sB + (cB >> 2);
    const ushort* gB = W + (size_t)nB * DIN + (cB & 3) * 8;

    const int col = lane & 15;
    const int kg  = (lane >> 4) * 8;
    const int c0  = kg >> 2;
    const int bc  = kg >> 3;
    const int ra  = wr + col;
    const int axr = ra & 7;
    const int aLo = ra * 32 + ((c0 ^ axr) << 2);
    const int aHi = ra * 32 + (((c0 + 1) ^ axr) << 2);
    const int nb0 = wc + col;
    const int bO  = (nb0 >> 1) * 64 +
                    (((((nb0 & 1) << 2) | bc) ^ ((nb0 >> 1) & 7)) << 3);

    f32x4 acc[4];
    #pragma unroll
    for (int ni = 0; ni < 4; ++ni) acc[ni] = (f32x4){0.f, 0.f, 0.f, 0.f};

#define STAGE(s_, t_) do {                                                    \
    gl16(gA + (t_) * 32, &As[(s_) * 2048 + w * 256]);                         \
    gl16(gB + (t_) * 32, &Bs[(s_) * 4096 + w * 512]);                         \
} while (0)

#define STEP(s_) do {                                                         \
    float4 lo = *(const float4*)&As[(s_) * 2048 + aLo];                       \
    float4 hi = *(const float4*)&As[(s_) * 2048 + aHi];                       \
    short8 bf0 = *(const short8*)&Bs[(s_) * 4096 + bO];                       \
    short8 bf1 = *(const short8*)&Bs[(s_) * 4096 + bO + 512];                 \
    short8 bf2 = *(const short8*)&Bs[(s_) * 4096 + bO + 1024];                \
    short8 bf3 = *(const short8*)&Bs[(s_) * 4096 + bO + 1536];                \
    short8 af0 = cvt8(lo, hi);                                                \
    acc[0] = __builtin_amdgcn_mfma_f32_16x16x32_bf16(af0, bf0, acc[0], 0, 0, 0); \
    acc[1] = __builtin_amdgcn_mfma_f32_16x16x32_bf16(af0, bf1, acc[1], 0, 0, 0); \
    acc[2] = __builtin_amdgcn_mfma_f32_16x16x32_bf16(af0, bf2, acc[2], 0, 0, 0); \
    acc[3] = __builtin_amdgcn_mfma_f32_16x16x32_bf16(af0, bf3, acc[3], 0, 0, 0); \
} while (0)

#define FENCE(n_) do {                                                        \
    asm volatile("s_waitcnt vmcnt(" #n_ ")" ::: "memory");                    \
    __builtin_amdgcn_sched_barrier(0);                                        \
    __builtin_amdgcn_s_barrier();                                             \
    __builtin_amdgcn_sched_barrier(0);                                        \
} while (0)

    STAGE(0, 0);
    STAGE(1, 1);
    FENCE(2);

    #pragma unroll 1
    for (int t = 0; t < 30; t += 3) {
        STAGE(2, t + 2); STEP(0); FENCE(2);
        STAGE(0, t + 3); STEP(1); FENCE(2);
        STAGE(1, t + 4); STEP(2); FENCE(2);
    }
    STEP(0);            // t=30
    FENCE(0);           // stage 31 complete
    STEP(1);            // t=31
    __syncthreads();    // all ring reads done; LDS free for Ys reuse

#undef STAGE
#undef STEP
#undef FENCE

    float bb[4];
    #pragma unroll
    for (int ni = 0; ni < 4; ++ni) bb[ni] = bias[wc + ni * 16 + col];

    ushort* Ys = (ushort*)As;           // 64x128 bf16 = 16 KB
    const int orow4 = (lane >> 4) * 4;
    #pragma unroll
    for (int ni = 0; ni < 4; ++ni)
        #pragma unroll
        for (int j = 0; j < 4; ++j) {
            float v = fmaxf(acc[ni][j] + bb[ni], 0.f);
            const int rl = wr + orow4 + j;
            const int cl = wc + ni * 16 + col;
            Ys[(rl * 128 + cl) ^ ((rl & 15) << 3)] = f2bf(v);
        }
    __syncthreads();

    if (p == 0) {
        // row-major write (qm reads q rows)
        const int r = tid >> 3, c = (tid & 7) * 16;
        const int swz = (r & 15) << 3;
        ushort* Yg = Y + (size_t)(row0 + r) * 128 + c;
        *(uint4*)&Yg[0] = *(const uint4*)&Ys[(r * 128 + c)     ^ swz];
        *(uint4*)&Yg[8] = *(const uint4*)&Ys[(r * 128 + c + 8) ^ swz];
    } else {
        // transposed write: Y[e][16384]; thread = (col e, 16-row group)
        const int c  = tid >> 2;            // 0..127
        const int rq = (tid & 3) * 16;      // 0,16,32,48
        ushort tmp[16];
        #pragma unroll
        for (int j = 0; j < 16; ++j) {
            const int r = rq + j;
            tmp[j] = Ys[(r * 128 + c) ^ ((r & 15) << 3)];
        }
        ushort* Yg = Y + (size_t)c * MROWS + row0 + rq;
        *(uint4*)&Yg[0] = *(const uint4*)&tmp[0];
        *(uint4*)&Yg[8] = *(const uint4*)&tmp[8];
    }
}

// ---------------------------------------------------------------------------
// ktv (MFMA): part[b*16+c][v][e] = sum_{r in chunk c} v[r][v]*k[r][e]
// A = kpT rows (M=e, K=r contiguous), B = vpT rows (N=v, K=r contiguous) —
// staging/fragment formulas are qm's validated ones. grid (16,8), 256 thr,
// 4 waves x (32e x 128v), K=128 per block. LDS-bounce epilogue for
// coalesced part writes.
// ---------------------------------------------------------------------------
__global__ __launch_bounds__(256) void ktv_kernel(
    const ushort* __restrict__ kpT, const ushort* __restrict__ vpT,
    ushort* __restrict__ part)
{
    const int c = blockIdx.x;           // r-chunk 0..15 (128 rows)
    const int b = blockIdx.y;
    const size_t rbase = (size_t)b * LK + c * 128;

    __shared__ __align__(16) ushort Ks[128 * 128];   // 32 KB
    __shared__ __align__(16) ushort Vs[128 * 128];   // 32 KB

    const int t = threadIdx.x;
    {
        const int e = t >> 1, half = (t & 1) * 64;
        const int swz = (e & 15) << 3;
        const ushort* sk = kpT + (size_t)e * MROWS + rbase + half;
        const ushort* sv = vpT + (size_t)e * MROWS + rbase + half;
        #pragma unroll
        for (int j = 0; j < 8; ++j) {
            *(uint4*)&Ks[(e * 128 + half + j * 8) ^ swz] = *(const uint4*)&sk[j * 8];
            *(uint4*)&Vs[(e * 128 + half + j * 8) ^ swz] = *(const uint4*)&sv[j * 8];
        }
    }
    __syncthreads();

    const int lane = t & 63;
    const int w    = t >> 6;
    const int we   = w * 32;            // wave's e-rows
    const int col  = lane & 15;
    const int kgrp = (lane >> 4) * 8;
    const int fswz = col << 3;

    f32x4 acc[2][8];
    #pragma unroll
    for (int mi = 0; mi < 2; ++mi)
        #pragma unroll
        for (int ni = 0; ni < 8; ++ni)
            acc[mi][ni] = (f32x4){0.f, 0.f, 0.f, 0.f};

    #pragma unroll
    for (int kk = 0; kk < 4; ++kk) {
        const int kb = kk * 32 + kgrp;
        short8 af[2], bfv[8];
        #pragma unroll
        for (int mi = 0; mi < 2; ++mi)
            af[mi] = *(const short8*)&Ks[((we + mi * 16 + col) * 128 + kb) ^ fswz];
        #pragma unroll
        for (int ni = 0; ni < 8; ++ni)
            bfv[ni] = *(const short8*)&Vs[((ni * 16 + col) * 128 + kb) ^ fswz];
        #pragma unroll
        for (int mi = 0; mi < 2; ++mi)
            #pragma unroll
            for (int ni = 0; ni < 8; ++ni)
                acc[mi][ni] = __builtin_amdgcn_mfma_f32_16x16x32_bf16(
                    af[mi], bfv[ni], acc[mi][ni], 0, 0, 0);
    }

    // bounce to LDS as [v][e] (e contiguous), swizzled, then coalesced write
    __syncthreads();
    const int orow4 = (lane >> 4) * 4;
    #pragma unroll
    for (int mi = 0; mi < 2; ++mi)
        #pragma unroll
        for (int ni = 0; ni < 8; ++ni)
            #pragma unroll
            for (int j = 0; j < 4; ++j) {
                const int e = we + mi * 16 + orow4 + j;   // M-dim
                const int v = ni * 16 + col;              // N-dim
                Ks[(v * 128 + e) ^ ((v & 15) << 3)] = f2bf(acc[mi][ni][j]);
            }
    __syncthreads();

    ushort* P = part + (size_t)(b * 16 + c) * 16384;
    {
        const int v = t >> 1, half = (t & 1) * 64;
        const int swz = (v & 15) << 3;
        #pragma unroll
        for (int j = 0; j < 8; ++j)
            *(uint4*)&P[v * 128 + half + j * 8] =
                *(const uint4*)&Ks[(v * 128 + half + j * 8) ^ swz];
    }
}

// ---------------------------------------------------------------------------
// reduce: Mt[b][v*128+e] = bf16(KSCALE * sum_{c<16} part[b*16+c][v*128+e])
// ---------------------------------------------------------------------------
__global__ __launch_bounds__(256) void reduce_kernel(
    const ushort* __restrict__ part, ushort* __restrict__ Mt)
{
    const int g = blockIdx.x * 256 + threadIdx.x;
    const int b = g >> 14, idx = g & 16383;
    const ushort* P = part + (size_t)b * 16 * 16384 + idx;
    float s = 0.f;
    #pragma unroll
    for (int c = 0; c < 16; ++c) s += bf2f(P[(size_t)c * 16384]);
    Mt[g] = f2bf(s * KSCALE);
}

// ---------------------------------------------------------------------------
// qm: out[row][v] = sum_e qp[row][e] * Mt[b][v][e]
// ---------------------------------------------------------------------------
__global__ __launch_bounds__(256) void qm_kernel(
    const ushort* __restrict__ qp, const ushort* __restrict__ Mt,
    float* __restrict__ out)
{
    const int row0 = blockIdx.x * 64;
    const int b = row0 >> 11;
    const ushort* Q = qp + (size_t)row0 * 128;
    const ushort* M = Mt + (size_t)b * 16384;

    __shared__ __align__(16) ushort As[64 * 128];
    __shared__ __align__(16) ushort Bs[128 * 128];

    const int t = threadIdx.x;
    {
        const int r = t >> 2, cc = (t & 3) * 32;
        const int swz = (r & 15) << 3;
        #pragma unroll
        for (int j = 0; j < 4; ++j)
            *(uint4*)&As[(r * 128 + cc + j * 8) ^ swz] = *(const uint4*)&Q[r * 128 + cc + j * 8];
    }
    {
        const int r = t >> 1, cc = (t & 1) * 64;
        const int swz = (r & 15) << 3;
        #pragma unroll
        for (int j = 0; j < 8; ++j)
            *(uint4*)&Bs[(r * 128 + cc + j * 8) ^ swz] = *(const uint4*)&M[r * 128 + cc + j * 8];
    }
    __syncthreads();

    const int lane = t & 63;
    const int wcol = (t >> 6) * 32;
    const int col  = lane & 15;
    const int kgrp = (lane >> 4) * 8;
    const int fswz = col << 3;

    f32x4 acc[4][2];
    #pragma unroll
    for (int mi = 0; mi < 4; ++mi)
        #pragma unroll
        for (int ni = 0; ni < 2; ++ni)
            acc[mi][ni] = (f32x4){0.f, 0.f, 0.f, 0.f};

    #pragma unroll
    for (int kk = 0; kk < 4; ++kk) {
        const int kb = kk * 32 + kgrp;
        short8 af[4], bfv[2];
        #pragma unroll
        for (int mi = 0; mi < 4; ++mi)
            af[mi] = *(const short8*)&As[((mi * 16 + col) * 128 + kb) ^ fswz];
        #pragma unroll
        for (int ni = 0; ni < 2; ++ni)
            bfv[ni] = *(const short8*)&Bs[((wcol + ni * 16 + col) * 128 + kb) ^ fswz];
        #pragma unroll
        for (int mi = 0; mi < 4; ++mi)
            #pragma unroll
            for (int ni = 0; ni < 2; ++ni)
                acc[mi][ni] = __builtin_amdgcn_mfma_f32_16x16x32_bf16(
                    af[mi], bfv[ni], acc[mi][ni], 0, 0, 0);
    }

    const int orow = (lane >> 4) * 4;
    #pragma unroll
    for (int mi = 0; mi < 4; ++mi)
        #pragma unroll
        for (int ni = 0; ni < 2; ++ni)
            #pragma unroll
            for (int j = 0; j < 4; ++j)
                out[(size_t)(row0 + mi * 16 + orow + j) * 128 + wcol + ni * 16 + col] =
                    acc[mi][ni][j];
}

// ---------------------------------------------------------------------------
extern "C" void kernel_launch(void* const* d_in, const int* in_sizes, int n_in,
                              void* d_out, int out_size, void* d_ws, size_t ws_size,
                              hipStream_t stream)
{
    const float* query = (const float*)d_in[0];
    const float* key   = (const float*)d_in[1];
    const float* value = (const float*)d_in[2];
    const float* Wq    = (const float*)d_in[3];
    const float* bq    = (const float*)d_in[4];
    const float* Wk    = (const float*)d_in[5];
    const float* bk    = (const float*)d_in[6];
    const float* Wv    = (const float*)d_in[7];
    const float* bv    = (const float*)d_in[8];
    float* out = (float*)d_out;

    ushort* qp   = (ushort*)d_ws;                    // 16384*128 bf16
    ushort* kpT  = qp + (size_t)MROWS * 128;         // [128][16384] bf16
    ushort* vpT  = kpT + (size_t)MROWS * 128;        // [128][16384] bf16
    ushort* Wt   = vpT + (size_t)MROWS * 128;        // 3*128*1024 bf16
    ushort* part = Wt + (size_t)3 * 128 * 1024;      // 8*16*16384 bf16 (4 MB)
    ushort* Mt   = part + (size_t)8 * 16 * 16384;    // 8*16384 bf16

    prep_kernel<<<dim3(16, 2, 3), 256, 0, stream>>>(Wq, Wk, Wv, Wt);
    proj_kernel<<<dim3(256, 3), 512, 0, stream>>>(query, bq, key, bk, value, bv,
                                                  Wt, qp, kpT, vpT);
    ktv_kernel<<<dim3(16, NB), 256, 0, stream>>>(kpT, vpT, part);
    reduce_kernel<<<512, 256, 0, stream>>>(part, Mt);
    qm_kernel<<<MROWS / 64, 256, 0, stream>>>(qp, Mt, out);
}